// Round 16
// baseline (127.494 us; speedup 1.0000x reference)
//
#include <hip/hip_runtime.h>
#include <hip/hip_bf16.h>
#include <math.h>

// Problem constants
#define NB    8          // batch
#define CIN   512        // in channels
#define HW    3136       // 56*56
#define CH    128        // attention channels
#define TCH   384        // 3*CH
#define SCALE 0.08838834764831845f   // 128^-0.5
#define QKSCALE 0.12751744f          // SCALE * log2(e), folded into Q at proj time
#define BNEPS 1e-5f
#define NSPLIT 5         // KV splits (49 tiles -> 10/10/10/10/9)
#define QB    128        // q rows per attn block (4 waves x 32)

typedef __attribute__((ext_vector_type(8)))  short bf16x8;
typedef __attribute__((ext_vector_type(4)))  short bf16x4;
typedef __attribute__((ext_vector_type(4)))  float f32x4;
typedef __attribute__((ext_vector_type(16))) float f32x16;

#define MFMA16(a, b, c) __builtin_amdgcn_mfma_f32_16x16x32_bf16((a), (b), (c), 0, 0, 0)
#define MFMA32(a, b, c) __builtin_amdgcn_mfma_f32_32x32x16_bf16((a), (b), (c), 0, 0, 0)

__device__ inline short f2bf(float f) {
    __hip_bfloat16 h = __float2bfloat16(f);
    return *reinterpret_cast<short*>(&h);
}
__device__ inline unsigned pack2bf(float a, float b) {
    return (unsigned)(unsigned short)f2bf(a) | ((unsigned)(unsigned short)f2bf(b) << 16);
}
__device__ inline unsigned cvtpk(float lo, float hi) {   // v_cvt_pk_bf16_f32 (RNE)
    unsigned r;
    asm("v_cvt_pk_bf16_f32 %0, %1, %2" : "=v"(r) : "v"(lo), "v"(hi));
    return r;
}
__device__ inline float bfraw2f(unsigned short u) {
    return __uint_as_float(((unsigned)u) << 16);
}
__device__ inline float exp2a(float x) {           // raw v_exp_f32 (2^x)
    float r; asm("v_exp_f32 %0, %1" : "=v"(r) : "v"(x)); return r;
}

// ---------------------------------------------------------------------------
// Kernel 0a: convert Ww and Zw f32 -> bf16.
// ---------------------------------------------------------------------------
__global__ __launch_bounds__(256) void cvt_wts(const float* __restrict__ Ww,
                                               const float* __restrict__ Zw,
                                               __hip_bfloat16* __restrict__ WwB,
                                               __hip_bfloat16* __restrict__ ZwB) {
    const int nW = TCH * CIN / 4;
    const int nZ = CIN * CH / 4;
    int i = blockIdx.x * 256 + threadIdx.x;
    if (i < nW) {
        float4 v = ((const float4*)Ww)[i];
        bf16x4 o; o[0] = f2bf(v.x); o[1] = f2bf(v.y); o[2] = f2bf(v.z); o[3] = f2bf(v.w);
        ((bf16x4*)WwB)[i] = o;
    } else if (i < nW + nZ) {
        int j = i - nW;
        float4 v = ((const float4*)Zw)[j];
        bf16x4 o; o[0] = f2bf(v.x); o[1] = f2bf(v.y); o[2] = f2bf(v.z); o[3] = f2bf(v.w);
        ((bf16x4*)ZwB)[j] = o;
    }
}

// ---------------------------------------------------------------------------
// Kernel 0b: xT[n][q][c] bf16 = transpose+cvt of x[n][c][q] f32. (unchanged)
// ---------------------------------------------------------------------------
__global__ __launch_bounds__(256) void xpose_kernel(const float* __restrict__ x,
                                                    __hip_bfloat16* __restrict__ xT) {
    const int n = blockIdx.z, c0 = blockIdx.y * 64, q0 = blockIdx.x * 64;
    const int tid = threadIdx.x;
    const int mr = tid >> 4, mq = tid & 15;

    __shared__ char T[64 * 128];

    const float* xp = x + ((size_t)(n * CIN + c0 + mr * 4)) * HW + q0 + mq * 4;
    float4 r0 = *(const float4*)(xp);
    float4 r1 = *(const float4*)(xp + HW);
    float4 r2 = *(const float4*)(xp + 2 * HW);
    float4 r3 = *(const float4*)(xp + 3 * HW);
    const float* f0 = (const float*)&r0; const float* f1 = (const float*)&r1;
    const float* f2 = (const float*)&r2; const float* f3 = (const float*)&r3;
#pragma unroll
    for (int j = 0; j < 4; ++j) {
        int q = mq * 4 + j;
        bf16x4 v; v[0] = f2bf(f0[j]); v[1] = f2bf(f1[j]);
                  v[2] = f2bf(f2[j]); v[3] = f2bf(f3[j]);
        *(bf16x4*)(T + q * 128 + ((mr * 8) ^ ((q & 15) << 3))) = v;
    }
    __syncthreads();

    __hip_bfloat16* og = xT + ((size_t)n * HW + q0) * CIN + c0;
#pragma unroll
    for (int it = 0; it < 2; ++it) {
        int ch = it * 256 + tid, rr = ch >> 3, o8 = ch & 7;
        int sw = (rr & 15) << 3;
        bf16x4 lo = *(const bf16x4*)(T + rr * 128 + ((o8 * 16) ^ sw));
        bf16x4 hi = *(const bf16x4*)(T + rr * 128 + ((o8 * 16 + 8) ^ sw));
        bf16x8 v; v[0] = lo[0]; v[1] = lo[1]; v[2] = lo[2]; v[3] = lo[3];
                  v[4] = hi[0]; v[5] = hi[1]; v[6] = hi[2]; v[7] = hi[3];
        *(bf16x8*)(og + (size_t)rr * CIN + o8 * 8) = v;
    }
}

// ---------------------------------------------------------------------------
// Kernel 1: proj via MFMA, BM=64, grid.x padded to 56 (XCD-aligned q tiles).
// ---------------------------------------------------------------------------
__global__ __launch_bounds__(256) void proj_kernel(const __hip_bfloat16* __restrict__ xT,
                                                   const __hip_bfloat16* __restrict__ WwB,
                                                   const float* __restrict__ Wb,
                                                   __hip_bfloat16* __restrict__ Qt,
                                                   __hip_bfloat16* __restrict__ Kt,
                                                   __hip_bfloat16* __restrict__ Vg) {
    const int q0 = blockIdx.x * 64;
    if (q0 >= HW) return;             // grid.x padded to 56 for XCD alignment
    const int n  = blockIdx.z;
    const int m0 = blockIdx.y * 64;
    const int tid = threadIdx.x;
    const int lane = tid & 63, wv = tid >> 6;
    const int lr = lane & 15, hi = lane >> 4;

    __shared__ char Aw[64 * 128];
    __shared__ char Bx[64 * 128];
    __shared__ char Ts[64 * 128];

    f32x4 acc[4] = {};
    const __hip_bfloat16* xn = xT + ((size_t)n * HW + q0) * CIN;

    for (int k0 = 0; k0 < CIN; k0 += 64) {
#pragma unroll
        for (int it = 0; it < 2; ++it) {
            int ch = it * 256 + tid, r = ch >> 3, o = ch & 7;
            int sw = (o * 16) ^ ((r & 7) << 4);
            bf16x8 a = *(const bf16x8*)(WwB + (size_t)(m0 + r) * CIN + k0 + o * 8);
            *(bf16x8*)(Aw + r * 128 + sw) = a;
            bf16x8 b = *(const bf16x8*)(xn + (size_t)r * CIN + k0 + o * 8);
            *(bf16x8*)(Bx + r * 128 + sw) = b;
        }
        __syncthreads();

        const int mrow = wv * 16 + lr;
#pragma unroll
        for (int ks = 0; ks < 2; ++ks) {
            bf16x8 af = *(const bf16x8*)(Aw + mrow * 128 +
                                         ((ks * 64 + hi * 16) ^ ((mrow & 7) << 4)));
#pragma unroll
            for (int kn = 0; kn < 4; ++kn) {
                int qrow = kn * 16 + lr;
                bf16x8 bfr = *(const bf16x8*)(Bx + qrow * 128 +
                                              ((ks * 64 + hi * 16) ^ ((qrow & 7) << 4)));
                acc[kn] = MFMA16(af, bfr, acc[kn]);
            }
        }
        __syncthreads();
    }

    const int region = m0 >> 7;     // 0=Q, 1=K, 2=V
    const int c0     = m0 & 127;
    const float oscale = (region == 0) ? QKSCALE : 1.0f;

    float bias[4];
#pragma unroll
    for (int reg = 0; reg < 4; ++reg) bias[reg] = Wb[m0 + wv * 16 + hi * 4 + reg];

#pragma unroll
    for (int kn = 0; kn < 4; ++kn)
#pragma unroll
        for (int reg = 0; reg < 4; ++reg) {
            __hip_bfloat16 v = __float2bfloat16((acc[kn][reg] + bias[reg]) * oscale);
            int row, colb;
            if (region < 2) { row = kn * 16 + lr; colb = (wv * 16 + hi * 4 + reg) * 2; }
            else            { row = wv * 16 + hi * 4 + reg; colb = (kn * 16 + lr) * 2; }
            *(__hip_bfloat16*)(Ts + row * 128 + (colb ^ ((row & 7) << 4))) = v;
        }
    __syncthreads();

    __hip_bfloat16* base;
    size_t rstride;
    if (region == 0)      { base = Qt + (size_t)n * HW * CH + (size_t)q0 * CH + c0; rstride = CH; }
    else if (region == 1) { base = Kt + (size_t)n * HW * CH + (size_t)q0 * CH + c0; rstride = CH; }
    else                  { base = Vg + (size_t)n * CH * HW + (size_t)c0 * HW + q0; rstride = HW; }

#pragma unroll
    for (int it = 0; it < 2; ++it) {
        int ch = it * 256 + tid, rr = ch >> 3, o = ch & 7;
        bf16x8 v = *(const bf16x8*)(Ts + rr * 128 + ((o * 16) ^ ((rr & 7) << 4)));
        *(bf16x8*)(base + (size_t)rr * rstride + o * 8) = v;
    }
}

// ---------------------------------------------------------------------------
// Kernel 2: flash attention, 32x32x16 MFMA, 4 waves x 32q, KVBLK=64.
// R16: double-buffered K/V LDS (64KB, still 2 blocks/CU since LDS-bound; VGPR
// budget at 2 waves/SIMD is 256 so no spill risk). ONE barrier per tile:
// {write next tile -> other buffer | prefetch t+2 | compute current} + bar.
// ---------------------------------------------------------------------------
__global__ __launch_bounds__(256, 2) void attn_kernel(
        const __hip_bfloat16* __restrict__ Qt,   // [NB][HW][CH], pre-scaled
        const __hip_bfloat16* __restrict__ Kt,   // [NB][HW][CH]
        const __hip_bfloat16* __restrict__ Vg,   // [NB][CH][HW]
        __hip_bfloat16* __restrict__ PO0,        // splits 0..3: [4][NB][HW][CH]
        __hip_bfloat16* __restrict__ PO4,        // split 4:     [NB][HW][CH]
        float* __restrict__ Mbuf,                // [NSPLIT][NB][HW] (exp2 domain)
        float* __restrict__ Lbuf) {
    const int n = blockIdx.x & 7, s = blockIdx.x >> 3;   // XCD = bid%8 = n
    const int q0 = blockIdx.y * QB;
    const int tid = threadIdx.x;             // 0..255
    const int lane = tid & 63, wv = tid >> 6;
    const int l31 = lane & 31, h = lane >> 5;

    __shared__ char smem[65536];
    char* KsA = smem;                 // buf A: K [64][256B], V [128][128B]
    char* VtA = smem + 16384;
    char* KsB = smem + 32768;         // buf B
    char* VtB = smem + 49152;

    const int t0 = s * 10;                    // 10/10/10/10/9
    const int t1 = (s == 4) ? 49 : (t0 + 10);

    const __hip_bfloat16* Kg = Kt + (size_t)n * HW * CH;
    const __hip_bfloat16* Vp = Vg + (size_t)n * CH * HW;

    // Q fragments: lane q = q0 + wv*32 + l31 (clamped in tail block)
    const int qg = q0 + wv * 32 + l31;
    const int qc = (qg < HW) ? qg : (HW - 1);
    const __hip_bfloat16* Qg = Qt + ((size_t)n * HW + qc) * CH + h * 8;
    bf16x8 qf[8];
#pragma unroll
    for (int cs = 0; cs < 8; ++cs) qf[cs] = *(const bf16x8*)(Qg + cs * 16);

    // staging geometry: K 64x256B (4 thr/row), V 128x128B (2 thr/row)
    const int kr = tid >> 2, kgb = (tid & 3) * 4;
    const int ksz = (kr & 7) ^ (((kr >> 3) & 1) << 3);
    const int vr = tid >> 1, vgb = (tid & 1) * 4;
    const int vsz = vr & 7;
    const __hip_bfloat16* Ksrc = Kg + (size_t)kr * CH;
    const __hip_bfloat16* Vsrc = Vp + (size_t)vr * HW;
    const int kdo = kr * 256;         // dest offset within K region
    const int vdo = vr * 128;         // dest offset within V region

    bf16x8 kreg[4], vreg[4];
    // prologue: load t0 -> regs -> buf A; barrier; load t0+1 -> regs
    {
        const int kk = t0 * 64;
#pragma unroll
        for (int i = 0; i < 4; ++i)
            kreg[i] = *(const bf16x8*)(Ksrc + (size_t)kk * CH + (kgb + i) * 8);
#pragma unroll
        for (int i = 0; i < 4; ++i)
            vreg[i] = *(const bf16x8*)(Vsrc + kk + (vgb + i) * 8);
    }
#pragma unroll
    for (int i = 0; i < 4; ++i) *(bf16x8*)(KsA + kdo + ((kgb + i) ^ ksz) * 16) = kreg[i];
#pragma unroll
    for (int i = 0; i < 4; ++i) *(bf16x8*)(VtA + vdo + ((vgb + i) ^ vsz) * 16) = vreg[i];
    __syncthreads();
    if (t0 + 1 < t1) {
        const int kk = (t0 + 1) * 64;
#pragma unroll
        for (int i = 0; i < 4; ++i)
            kreg[i] = *(const bf16x8*)(Ksrc + (size_t)kk * CH + (kgb + i) * 8);
#pragma unroll
        for (int i = 0; i < 4; ++i)
            vreg[i] = *(const bf16x8*)(Vsrc + kk + (vgb + i) * 8);
    }

    // fragment-read swizzles
    const int rsw = (l31 & 7) ^ (((l31 >> 3) & 1) << 3);
    const int vrsw = l31 & 7;

    f32x16 O[4] = {};            // O^T: c = ct*32 + crow(reg,h), q = l31
    float m_i = -1e30f, l_i = 0.f;

    // one iteration: write regs(t+1)->NXT, prefetch t+2, compute on CUR, bar
    auto ITER = [&](int t, char* CK, char* CV, char* NK, char* NV) {
        if (t + 1 < t1) {
#pragma unroll
            for (int i = 0; i < 4; ++i) *(bf16x8*)(NK + kdo + ((kgb + i) ^ ksz) * 16) = kreg[i];
#pragma unroll
            for (int i = 0; i < 4; ++i) *(bf16x8*)(NV + vdo + ((vgb + i) ^ vsz) * 16) = vreg[i];
        }
        if (t + 2 < t1) {
            const int kk = (t + 2) * 64;
#pragma unroll
            for (int i = 0; i < 4; ++i)
                kreg[i] = *(const bf16x8*)(Ksrc + (size_t)kk * CH + (kgb + i) * 8);
#pragma unroll
            for (int i = 0; i < 4; ++i)
                vreg[i] = *(const bf16x8*)(Vsrc + kk + (vgb + i) * 8);
        }

        // ---- S^T = K Q^T (2 k-subtiles of 32)
        f32x16 sa0 = {}, sa1 = {};
        __builtin_amdgcn_s_setprio(1);
#pragma unroll
        for (int cs = 0; cs < 8; ++cs) {
            int goff = ((cs * 2 + h) ^ rsw) * 16;
            bf16x8 k0f = *(const bf16x8*)(CK + l31 * 256 + goff);
            bf16x8 k1f = *(const bf16x8*)(CK + (32 + l31) * 256 + goff);
            sa0 = MFMA32(k0f, qf[cs], sa0);
            sa1 = MFMA32(k1f, qf[cs], sa1);
        }
        __builtin_amdgcn_s_setprio(0);

        // ---- tree-reduced max (depth 5 + 1 cross-half shuffle)
        float tm[16];
#pragma unroll
        for (int r = 0; r < 16; ++r) tm[r] = fmaxf(sa0[r], sa1[r]);
#pragma unroll
        for (int st = 8; st >= 1; st >>= 1)
#pragma unroll
            for (int r = 0; r < st; ++r) tm[r] = fmaxf(tm[r], tm[r + st]);
        float pmax = tm[0];
        pmax = fmaxf(pmax, __shfl_xor(pmax, 32));

        // ---- defer-max: rescale only when max grew by > 8 (exp2 domain)
        if (__any(pmax > m_i + 8.0f)) {
            float nm = fmaxf(m_i, pmax);
            float f  = exp2a(m_i - nm);
            l_i *= f; m_i = nm;
#pragma unroll
            for (int ct = 0; ct < 4; ++ct)
#pragma unroll
                for (int r = 0; r < 16; ++r) O[ct][r] *= f;
        }

        // ---- P = exp2(s - m), tree-reduced row sum
#pragma unroll
        for (int r = 0; r < 16; ++r) sa0[r] = exp2a(sa0[r] - m_i);
#pragma unroll
        for (int r = 0; r < 16; ++r) sa1[r] = exp2a(sa1[r] - m_i);
        float ts[16];
#pragma unroll
        for (int r = 0; r < 16; ++r) ts[r] = sa0[r] + sa1[r];
#pragma unroll
        for (int st = 8; st >= 1; st >>= 1)
#pragma unroll
            for (int r = 0; r < st; ++r) ts[r] += ts[r + st];
        float rs = ts[0];
        rs += __shfl_xor(rs, 32);
        l_i += rs;

        // ---- pack P (v_cvt_pk_bf16_f32), build PV B-frags via permlane32
        union { unsigned u[4]; bf16x8 v; } pf0, pf1, pf2, pf3;
        {
            unsigned w0 = cvtpk(sa0[0],  sa0[1]),  w1 = cvtpk(sa0[2],  sa0[3]);
            unsigned w2 = cvtpk(sa0[4],  sa0[5]),  w3 = cvtpk(sa0[6],  sa0[7]);
            unsigned w4 = cvtpk(sa0[8],  sa0[9]),  w5 = cvtpk(sa0[10], sa0[11]);
            unsigned w6 = cvtpk(sa0[12], sa0[13]), w7 = cvtpk(sa0[14], sa0[15]);
            asm("v_permlane32_swap_b32 %0, %1" : "+v"(w0), "+v"(w2));
            asm("v_permlane32_swap_b32 %0, %1" : "+v"(w1), "+v"(w3));
            asm("v_permlane32_swap_b32 %0, %1" : "+v"(w4), "+v"(w6));
            asm("v_permlane32_swap_b32 %0, %1" : "+v"(w5), "+v"(w7));
            pf0.u[0] = w0; pf0.u[1] = w1; pf0.u[2] = w2; pf0.u[3] = w3;
            pf1.u[0] = w4; pf1.u[1] = w5; pf1.u[2] = w6; pf1.u[3] = w7;
        }
        {
            unsigned w0 = cvtpk(sa1[0],  sa1[1]),  w1 = cvtpk(sa1[2],  sa1[3]);
            unsigned w2 = cvtpk(sa1[4],  sa1[5]),  w3 = cvtpk(sa1[6],  sa1[7]);
            unsigned w4 = cvtpk(sa1[8],  sa1[9]),  w5 = cvtpk(sa1[10], sa1[11]);
            unsigned w6 = cvtpk(sa1[12], sa1[13]), w7 = cvtpk(sa1[14], sa1[15]);
            asm("v_permlane32_swap_b32 %0, %1" : "+v"(w0), "+v"(w2));
            asm("v_permlane32_swap_b32 %0, %1" : "+v"(w1), "+v"(w3));
            asm("v_permlane32_swap_b32 %0, %1" : "+v"(w4), "+v"(w6));
            asm("v_permlane32_swap_b32 %0, %1" : "+v"(w5), "+v"(w7));
            pf2.u[0] = w0; pf2.u[1] = w1; pf2.u[2] = w2; pf2.u[3] = w3;
            pf3.u[0] = w4; pf3.u[1] = w5; pf3.u[2] = w6; pf3.u[3] = w7;
        }

        // ---- O^T += V P^T ; V A-frags from LDS
        __builtin_amdgcn_s_setprio(1);
#pragma unroll
        for (int ct = 0; ct < 4; ++ct) {
            const char* vrow = CV + (ct * 32 + l31) * 128;
            bf16x8 v0 = *(const bf16x8*)(vrow + ((0 + h) ^ vrsw) * 16);
            bf16x8 v1 = *(const bf16x8*)(vrow + ((2 + h) ^ vrsw) * 16);
            bf16x8 v2 = *(const bf16x8*)(vrow + ((4 + h) ^ vrsw) * 16);
            bf16x8 v3 = *(const bf16x8*)(vrow + ((6 + h) ^ vrsw) * 16);
            O[ct] = MFMA32(v0, pf0.v, O[ct]);
            O[ct] = MFMA32(v1, pf1.v, O[ct]);
            O[ct] = MFMA32(v2, pf2.v, O[ct]);
            O[ct] = MFMA32(v3, pf3.v, O[ct]);
        }
        __builtin_amdgcn_s_setprio(0);

        __syncthreads();   // the ONLY barrier: covers compute-CUR and write-NXT
    };

    for (int t = t0; t < t1; t += 2) {
        ITER(t, KsA, VtA, KsB, VtB);
        if (t + 1 < t1) ITER(t + 1, KsB, VtB, KsA, VtA);
    }

    // ---- epilogue: unnormalized O~ -> smem [128 q][256B] bf16, coalesced out
    const int qrow = wv * 32 + l31;
    const int esw  = (qrow & 7) << 4;
#pragma unroll
    for (int ct = 0; ct < 4; ++ct)
#pragma unroll
        for (int i = 0; i < 8; ++i) {
            int c = ct * 32 + 2 * (i & 1) + 8 * (i >> 1) + 4 * h;
            unsigned u = pack2bf(O[ct][2 * i], O[ct][2 * i + 1]);
            *(unsigned*)(smem + qrow * 256 + ((c * 2) ^ esw)) = u;
        }
    __syncthreads();
    __hip_bfloat16* pbase = (s < 4) ? (PO0 + (size_t)s * NB * HW * CH) : PO4;
    __hip_bfloat16* pg = pbase + ((size_t)n * HW + q0) * CH;
#pragma unroll
    for (int it = 0; it < 8; ++it) {
        int ch = it * 256 + tid, r = ch >> 4, g = ch & 15;
        if (q0 + r < HW) {
            bf16x8 v = *(const bf16x8*)(smem + r * 256 + ((g * 16) ^ ((r & 7) << 4)));
            *(bf16x8*)(pg + (size_t)r * CH + g * 8) = v;
        }
    }
    if (h == 0 && qg < HW) {
        size_t base = (size_t)(s * NB + n) * HW + qg;
        Mbuf[base] = m_i; Lbuf[base] = l_i;
    }
}

// ---------------------------------------------------------------------------
// Kernel 2b: merge KV-split partials (exp2 domain) -> att bf16 [n][q][c].
// ---------------------------------------------------------------------------
__global__ __launch_bounds__(256) void merge_kernel(
        const __hip_bfloat16* __restrict__ PO0,
        const __hip_bfloat16* __restrict__ PO4,
        const float* __restrict__ Mbuf,
        const float* __restrict__ Lbuf,
        __hip_bfloat16* __restrict__ att) {
    const int idx = blockIdx.x * 256 + threadIdx.x;
    const int nq = idx >> 4;
    const int c0 = (idx & 15) * 8;
    const size_t NHW = (size_t)NB * HW;

    float m[NSPLIT], l[NSPLIT];
#pragma unroll
    for (int s = 0; s < NSPLIT; ++s) { m[s] = Mbuf[s * NHW + nq]; l[s] = Lbuf[s * NHW + nq]; }
    float M = m[0];
#pragma unroll
    for (int s = 1; s < NSPLIT; ++s) M = fmaxf(M, m[s]);
    float w[NSPLIT], denom = 0.f;
#pragma unroll
    for (int s = 0; s < NSPLIT; ++s) { w[s] = exp2f(m[s] - M); denom += w[s] * l[s]; }
    float rinv = 1.f / denom;

    float acc[8] = {};
#pragma unroll
    for (int s = 0; s < NSPLIT; ++s) {
        const __hip_bfloat16* pbase = (s < 4) ? (PO0 + (size_t)s * NHW * CH) : PO4;
        union { bf16x8 v; unsigned short u[8]; } p;
        p.v = *(const bf16x8*)(pbase + (size_t)nq * CH + c0);
#pragma unroll
        for (int j = 0; j < 8; ++j) acc[j] += w[s] * bfraw2f(p.u[j]);
    }
    union { bf16x8 v; unsigned short u[8]; } ov;
#pragma unroll
    for (int j = 0; j < 8; ++j) ov.u[j] = (unsigned short)f2bf(acc[j] * rinv);
    *(bf16x8*)(att + (size_t)nq * CH + c0) = ov.v;
}

// ---------------------------------------------------------------------------
// Kernel 3: z = ZwB @ att[n] via MFMA (K=128), BN + residual, grid.x = 56.
// ---------------------------------------------------------------------------
__global__ __launch_bounds__(256) void zbn_kernel(const __hip_bfloat16* __restrict__ att,
                                                  const __hip_bfloat16* __restrict__ ZwB,
                                                  const float* __restrict__ gamma,
                                                  const float* __restrict__ beta,
                                                  const float* __restrict__ mean,
                                                  const float* __restrict__ var,
                                                  const float* __restrict__ x,
                                                  float* __restrict__ out) {
    const int q0 = blockIdx.x * 64;
    if (q0 >= HW) return;             // grid.x padded to 56 for XCD alignment
    const int n  = blockIdx.z;
    const int m0 = blockIdx.y * 64;
    const int tid = threadIdx.x;
    const int lane = tid & 63, wv = tid >> 6;
    const int lr = lane & 15, hi = lane >> 4;

    __shared__ char smem[32768];
    char* Az = smem;
    char* Ba = smem + 16384;

#pragma unroll
    for (int it = 0; it < 4; ++it) {
        int ch = it * 256 + tid, r = ch >> 4, o = ch & 15;
        int sw = (o * 16) ^ ((r & 7) << 4);
        bf16x8 a = *(const bf16x8*)(ZwB + (size_t)(m0 + r) * CH + o * 8);
        *(bf16x8*)(Az + r * 256 + sw) = a;
        bf16x8 b = *(const bf16x8*)(att + ((size_t)n * HW + q0 + r) * CH + o * 8);
        *(bf16x8*)(Ba + r * 256 + sw) = b;
    }
    __syncthreads();

    f32x4 acc[4] = {};
    const int mrow = wv * 16 + lr;
#pragma unroll
    for (int ks = 0; ks < 4; ++ks) {
        bf16x8 af = *(const bf16x8*)(Az + mrow * 256 +
                                     ((ks * 64 + hi * 16) ^ ((mrow & 7) << 4)));
#pragma unroll
        for (int kn = 0; kn < 4; ++kn) {
            int qrow = kn * 16 + lr;
            bf16x8 bfr = *(const bf16x8*)(Ba + qrow * 256 +
                                          ((ks * 64 + hi * 16) ^ ((qrow & 7) << 4)));
            acc[kn] = MFMA16(af, bfr, acc[kn]);
        }
    }
    __syncthreads();

    float inv[4], add[4];
#pragma unroll
    for (int reg = 0; reg < 4; ++reg) {
        int m = m0 + wv * 16 + hi * 4 + reg;
        inv[reg] = gamma[m] * rsqrtf(var[m] + BNEPS);
        add[reg] = beta[m] - mean[m] * inv[reg];
    }

#pragma unroll
    for (int kn = 0; kn < 4; ++kn)
#pragma unroll
        for (int reg = 0; reg < 4; ++reg) {
            int row = wv * 16 + hi * 4 + reg;
            int colb = (kn * 16 + lr) * 4;
            *(float*)(smem + row * 256 + (colb ^ ((row & 7) << 4))) =
                acc[kn][reg] * inv[reg] + add[reg];
        }
    __syncthreads();

#pragma unroll
    for (int it = 0; it < 4; ++it) {
        int ch = it * 256 + tid, rr = ch >> 4, o = ch & 15;
        f32x4 v = *(const f32x4*)(smem + rr * 256 + ((o * 16) ^ ((rr & 7) << 4)));
        size_t idx = (size_t)n * CIN * HW + (size_t)(m0 + rr) * HW + q0 + o * 4;
        float4 xv = *(const float4*)(x + idx);
        float4 ov; ov.x = v[0] + xv.x; ov.y = v[1] + xv.y;
                   ov.z = v[2] + xv.z; ov.w = v[3] + xv.w;
        *(float4*)(out + idx) = ov;
    }
}

// ---------------------------------------------------------------------------
extern "C" void kernel_launch(void* const* d_in, const int* in_sizes, int n_in,
                              void* d_out, int out_size, void* d_ws, size_t ws_size,
                              hipStream_t stream) {
    const float* x     = (const float*)d_in[0];
    const float* Ww    = (const float*)d_in[1];
    const float* Wb    = (const float*)d_in[2];
    const float* Zw    = (const float*)d_in[3];
    const float* gamma = (const float*)d_in[4];
    const float* beta  = (const float*)d_in[5];
    const float* mean  = (const float*)d_in[6];
    const float* var   = (const float*)d_in[7];
    float* out = (float*)d_out;

    // d_out scratch chain (51.38 MB), all dead before zbn writes out:
    //   [0, 25.69M)      xT          (xpose -> proj)
    //   [25.69, 44.96M)  Qt/Kt/Vg    (proj -> attn)
    //   [0, 25.69M)      PO splits 0-3 (attn -> merge; overlays dead xT)
    //   [44.96, 51.38M)  PO split 4    (unused tail, exactly 6.42MB)
    const size_t xT_bytes  = (size_t)NB * HW * CIN * 2;
    const size_t qkv_bytes = (size_t)NB * HW * CH * 2;
    char* ob = (char*)d_out;
    __hip_bfloat16* xT  = (__hip_bfloat16*)ob;
    __hip_bfloat16* Qt  = (__hip_bfloat16*)(ob + xT_bytes);
    __hip_bfloat16* Kt  = (__hip_bfloat16*)(ob + xT_bytes + qkv_bytes);
    __hip_bfloat16* Vgb = (__hip_bfloat16*)(ob + xT_bytes + 2 * qkv_bytes);
    __hip_bfloat16* PO0 = (__hip_bfloat16*)ob;
    __hip_bfloat16* PO4 = (__hip_bfloat16*)(ob + xT_bytes + 3 * qkv_bytes);

    char* w = (char*)d_ws;
    __hip_bfloat16* attb = (__hip_bfloat16*)w;                       w += qkv_bytes;
    __hip_bfloat16* WwB  = (__hip_bfloat16*)w;                       w += (size_t)TCH * CIN * 2;
    __hip_bfloat16* ZwB  = (__hip_bfloat16*)w;                       w += (size_t)CIN * CH * 2;
    float* Mbuf = (float*)w;                                         w += (size_t)NSPLIT * NB * HW * 4;
    float* Lbuf = (float*)w;

    cvt_wts<<<dim3(256), 256, 0, stream>>>(Ww, Zw, WwB, ZwB);
    xpose_kernel<<<dim3(HW / 64, CIN / 64, NB), 256, 0, stream>>>(x, xT);
    proj_kernel<<<dim3(56, TCH / 64, NB), 256, 0, stream>>>(xT, WwB, Wb, Qt, Kt, Vgb);
    attn_kernel<<<dim3(NB * NSPLIT, (HW + QB - 1) / QB), 256, 0, stream>>>(
        Qt, Kt, Vgb, PO0, PO4, Mbuf, Lbuf);
    merge_kernel<<<dim3(NB * HW * 16 / 256), 256, 0, stream>>>(PO0, PO4, Mbuf, Lbuf, attb);
    zbn_kernel<<<dim3(56, CIN / 64, NB), 256, 0, stream>>>(attb, ZwB, gamma, beta,
                                                           mean, var, x, out);
}

// Round 18
// 125.976 us; speedup vs baseline: 1.0121x; 1.0121x over previous
//
#include <hip/hip_runtime.h>
#include <hip/hip_bf16.h>
#include <math.h>

// Problem constants
#define NB    8          // batch
#define CIN   512        // in channels
#define HW    3136       // 56*56
#define CH    128        // attention channels
#define TCH   384        // 3*CH
#define SCALE 0.08838834764831845f   // 128^-0.5
#define QKSCALE 0.12751744f          // SCALE * log2(e), folded into Q at proj time
#define BNEPS 1e-5f
#define NSPLIT 5         // KV splits (49 tiles -> 10/10/10/10/9)
#define QB    128        // q rows per attn block (4 waves x 32)

typedef __attribute__((ext_vector_type(8)))  short bf16x8;
typedef __attribute__((ext_vector_type(4)))  short bf16x4;
typedef __attribute__((ext_vector_type(4)))  float f32x4;
typedef __attribute__((ext_vector_type(16))) float f32x16;

#define MFMA16(a, b, c) __builtin_amdgcn_mfma_f32_16x16x32_bf16((a), (b), (c), 0, 0, 0)
#define MFMA32(a, b, c) __builtin_amdgcn_mfma_f32_32x32x16_bf16((a), (b), (c), 0, 0, 0)

__device__ inline short f2bf(float f) {
    __hip_bfloat16 h = __float2bfloat16(f);
    return *reinterpret_cast<short*>(&h);
}
__device__ inline unsigned pack2bf(float a, float b) {
    return (unsigned)(unsigned short)f2bf(a) | ((unsigned)(unsigned short)f2bf(b) << 16);
}
__device__ inline unsigned cvtpk(float lo, float hi) {   // v_cvt_pk_bf16_f32 (RNE)
    unsigned r;
    asm("v_cvt_pk_bf16_f32 %0, %1, %2" : "=v"(r) : "v"(lo), "v"(hi));
    return r;
}
__device__ inline float bfraw2f(unsigned short u) {
    return __uint_as_float(((unsigned)u) << 16);
}
__device__ inline float exp2a(float x) {           // raw v_exp_f32 (2^x)
    float r; asm("v_exp_f32 %0, %1" : "=v"(r) : "v"(x)); return r;
}

// ---------------------------------------------------------------------------
// Kernel 0: convert Ww and Zw f32 -> bf16.
// ---------------------------------------------------------------------------
__global__ __launch_bounds__(256) void cvt_wts(const float* __restrict__ Ww,
                                               const float* __restrict__ Zw,
                                               __hip_bfloat16* __restrict__ WwB,
                                               __hip_bfloat16* __restrict__ ZwB) {
    const int nW = TCH * CIN / 4;
    const int nZ = CIN * CH / 4;
    int i = blockIdx.x * 256 + threadIdx.x;
    if (i < nW) {
        float4 v = ((const float4*)Ww)[i];
        bf16x4 o; o[0] = f2bf(v.x); o[1] = f2bf(v.y); o[2] = f2bf(v.z); o[3] = f2bf(v.w);
        ((bf16x4*)WwB)[i] = o;
    } else if (i < nW + nZ) {
        int j = i - nW;
        float4 v = ((const float4*)Zw)[j];
        bf16x4 o; o[0] = f2bf(v.x); o[1] = f2bf(v.y); o[2] = f2bf(v.z); o[3] = f2bf(v.w);
        ((bf16x4*)ZwB)[j] = o;
    }
}

// ---------------------------------------------------------------------------
// Kernel 1: proj via MFMA with FUSED x-transpose (xpose kernel removed).
// B-staging loads x f32 [c][q] coalesced, micro-transposes 4x4 in registers,
// writes bf16x4 into Bx with granule convention phys = logical ^ (q&7).
// grid.x padded to 56 (XCD-aligned q tiles; x re-reads L2-hit).
// ---------------------------------------------------------------------------
__global__ __launch_bounds__(256) void proj_kernel(const float* __restrict__ x,
                                                   const __hip_bfloat16* __restrict__ WwB,
                                                   const float* __restrict__ Wb,
                                                   __hip_bfloat16* __restrict__ Qt,
                                                   __hip_bfloat16* __restrict__ Kt,
                                                   __hip_bfloat16* __restrict__ Vg) {
    const int q0 = blockIdx.x * 64;
    if (q0 >= HW) return;             // grid.x padded to 56 for XCD alignment
    const int n  = blockIdx.z;
    const int m0 = blockIdx.y * 64;
    const int tid = threadIdx.x;
    const int lane = tid & 63, wv = tid >> 6;
    const int lr = lane & 15, hi = lane >> 4;

    __shared__ char Aw[64 * 128];
    __shared__ char Bx[64 * 128];
    __shared__ char Ts[64 * 128];

    // fused-transpose staging geometry: mr = c-group (4 rows), mq = q-group (4)
    const int mr = tid >> 4, mq = tid & 15;

    f32x4 acc[4] = {};

    for (int k0 = 0; k0 < CIN; k0 += 64) {
        // A tile: 64m x 64c bf16 (2 granule-chunks per thread)
#pragma unroll
        for (int it = 0; it < 2; ++it) {
            int ch = it * 256 + tid, r = ch >> 3, o = ch & 7;
            int sw = (o * 16) ^ ((r & 7) << 4);
            bf16x8 a = *(const bf16x8*)(WwB + (size_t)(m0 + r) * CIN + k0 + o * 8);
            *(bf16x8*)(Aw + r * 128 + sw) = a;
        }
        // B tile: x f32 [c][q] -> transpose -> Bx [q][64 c] bf16
        {
            const float* xp = x + ((size_t)(n * CIN + k0 + mr * 4)) * HW + q0 + mq * 4;
            float4 r0 = *(const float4*)(xp);
            float4 r1 = *(const float4*)(xp + HW);
            float4 r2 = *(const float4*)(xp + 2 * HW);
            float4 r3 = *(const float4*)(xp + 3 * HW);
            const float* f0 = (const float*)&r0; const float* f1 = (const float*)&r1;
            const float* f2 = (const float*)&r2; const float* f3 = (const float*)&r3;
#pragma unroll
            for (int j = 0; j < 4; ++j) {
                int q = mq * 4 + j;
                bf16x4 v; v[0] = f2bf(f0[j]); v[1] = f2bf(f1[j]);
                          v[2] = f2bf(f2[j]); v[3] = f2bf(f3[j]);
                // logical granule mr>>1 (8B half mr&1), physical ^= (q&7)
                *(bf16x4*)(Bx + q * 128 + (((mr >> 1) ^ (q & 7)) << 4) + (mr & 1) * 8) = v;
            }
        }
        __syncthreads();

        const int mrow = wv * 16 + lr;
#pragma unroll
        for (int ks = 0; ks < 2; ++ks) {
            bf16x8 af = *(const bf16x8*)(Aw + mrow * 128 +
                                         ((ks * 64 + hi * 16) ^ ((mrow & 7) << 4)));
#pragma unroll
            for (int kn = 0; kn < 4; ++kn) {
                int qrow = kn * 16 + lr;
                bf16x8 bfr = *(const bf16x8*)(Bx + qrow * 128 +
                                              ((ks * 64 + hi * 16) ^ ((qrow & 7) << 4)));
                acc[kn] = MFMA16(af, bfr, acc[kn]);
            }
        }
        __syncthreads();
    }

    const int region = m0 >> 7;     // 0=Q, 1=K, 2=V
    const int c0     = m0 & 127;
    const float oscale = (region == 0) ? QKSCALE : 1.0f;

    float bias[4];
#pragma unroll
    for (int reg = 0; reg < 4; ++reg) bias[reg] = Wb[m0 + wv * 16 + hi * 4 + reg];

#pragma unroll
    for (int kn = 0; kn < 4; ++kn)
#pragma unroll
        for (int reg = 0; reg < 4; ++reg) {
            __hip_bfloat16 v = __float2bfloat16((acc[kn][reg] + bias[reg]) * oscale);
            int row, colb;
            if (region < 2) { row = kn * 16 + lr; colb = (wv * 16 + hi * 4 + reg) * 2; }
            else            { row = wv * 16 + hi * 4 + reg; colb = (kn * 16 + lr) * 2; }
            *(__hip_bfloat16*)(Ts + row * 128 + (colb ^ ((row & 7) << 4))) = v;
        }
    __syncthreads();

    __hip_bfloat16* base;
    size_t rstride;
    if (region == 0)      { base = Qt + (size_t)n * HW * CH + (size_t)q0 * CH + c0; rstride = CH; }
    else if (region == 1) { base = Kt + (size_t)n * HW * CH + (size_t)q0 * CH + c0; rstride = CH; }
    else                  { base = Vg + (size_t)n * CH * HW + (size_t)c0 * HW + q0; rstride = HW; }

#pragma unroll
    for (int it = 0; it < 2; ++it) {
        int ch = it * 256 + tid, rr = ch >> 3, o = ch & 7;
        bf16x8 v = *(const bf16x8*)(Ts + rr * 128 + ((o * 16) ^ ((rr & 7) << 4)));
        *(bf16x8*)(base + (size_t)rr * rstride + o * 8) = v;
    }
}

// ---------------------------------------------------------------------------
// Kernel 2: flash attention (R15 proven version).
// ---------------------------------------------------------------------------
__global__ __launch_bounds__(256, 2) void attn_kernel(
        const __hip_bfloat16* __restrict__ Qt,   // [NB][HW][CH], pre-scaled
        const __hip_bfloat16* __restrict__ Kt,   // [NB][HW][CH]
        const __hip_bfloat16* __restrict__ Vg,   // [NB][CH][HW]
        __hip_bfloat16* __restrict__ PO0,        // splits 0..3: [4][NB][HW][CH]
        __hip_bfloat16* __restrict__ PO4,        // split 4:     [NB][HW][CH]
        float* __restrict__ Mbuf,                // [NSPLIT][NB][HW] (exp2 domain)
        float* __restrict__ Lbuf) {
    const int n = blockIdx.x & 7, s = blockIdx.x >> 3;   // XCD = bid%8 = n
    const int q0 = blockIdx.y * QB;
    const int tid = threadIdx.x;             // 0..255
    const int lane = tid & 63, wv = tid >> 6;
    const int l31 = lane & 31, h = lane >> 5;

    __shared__ char smem[32768];
    char* Ks = smem;            // [64 k][16 granules of 16B], 4-bit granule swz
    char* Vt = smem + 16384;    // [128 c][8 granules of 16B], 3-bit granule swz

    const int t0 = s * 10;                    // 10/10/10/10/9
    const int t1 = (s == 4) ? 49 : (t0 + 10);

    const __hip_bfloat16* Kg = Kt + (size_t)n * HW * CH;
    const __hip_bfloat16* Vp = Vg + (size_t)n * CH * HW;

    // Q fragments: lane q = q0 + wv*32 + l31 (clamped in tail block)
    const int qg = q0 + wv * 32 + l31;
    const int qc = (qg < HW) ? qg : (HW - 1);
    const __hip_bfloat16* Qg = Qt + ((size_t)n * HW + qc) * CH + h * 8;
    bf16x8 qf[8];
#pragma unroll
    for (int cs = 0; cs < 8; ++cs) qf[cs] = *(const bf16x8*)(Qg + cs * 16);

    // staging geometry: K 64x256B (4 thr/row), V 128x128B (2 thr/row)
    const int kr = tid >> 2, kgb = (tid & 3) * 4;
    const int ksz = (kr & 7) ^ (((kr >> 3) & 1) << 3);
    const int vr = tid >> 1, vgb = (tid & 1) * 4;
    const int vsz = vr & 7;
    const __hip_bfloat16* Ksrc = Kg + (size_t)kr * CH;
    const __hip_bfloat16* Vsrc = Vp + (size_t)vr * HW;
    char* Kd = Ks + kr * 256;
    char* Vd = Vt + vr * 128;

    bf16x8 kreg[4], vreg[4];
    {
        const int kk = t0 * 64;
#pragma unroll
        for (int i = 0; i < 4; ++i)
            kreg[i] = *(const bf16x8*)(Ksrc + (size_t)kk * CH + (kgb + i) * 8);
#pragma unroll
        for (int i = 0; i < 4; ++i)
            vreg[i] = *(const bf16x8*)(Vsrc + kk + (vgb + i) * 8);
    }
#pragma unroll
    for (int i = 0; i < 4; ++i) *(bf16x8*)(Kd + ((kgb + i) ^ ksz) * 16) = kreg[i];
#pragma unroll
    for (int i = 0; i < 4; ++i) *(bf16x8*)(Vd + ((vgb + i) ^ vsz) * 16) = vreg[i];
    __syncthreads();

    // fragment-read swizzles
    const int rsw = (l31 & 7) ^ (((l31 >> 3) & 1) << 3);
    const int vrsw = l31 & 7;

    f32x16 O[4] = {};            // O^T: c = ct*32 + crow(reg,h), q = l31
    float m_i = -1e30f, l_i = 0.f;

    for (int t = t0; t < t1; ++t) {
        // prefetch next tile into registers (hides under MFMA+softmax)
        if (t + 1 < t1) {
            const int kk = (t + 1) * 64;
#pragma unroll
            for (int i = 0; i < 4; ++i)
                kreg[i] = *(const bf16x8*)(Ksrc + (size_t)kk * CH + (kgb + i) * 8);
#pragma unroll
            for (int i = 0; i < 4; ++i)
                vreg[i] = *(const bf16x8*)(Vsrc + kk + (vgb + i) * 8);
        }

        // ---- S^T = K Q^T (2 k-subtiles of 32)
        f32x16 sa0 = {}, sa1 = {};
        __builtin_amdgcn_s_setprio(1);
#pragma unroll
        for (int cs = 0; cs < 8; ++cs) {
            int goff = ((cs * 2 + h) ^ rsw) * 16;
            bf16x8 k0f = *(const bf16x8*)(Ks + l31 * 256 + goff);
            bf16x8 k1f = *(const bf16x8*)(Ks + (32 + l31) * 256 + goff);
            sa0 = MFMA32(k0f, qf[cs], sa0);
            sa1 = MFMA32(k1f, qf[cs], sa1);
        }
        __builtin_amdgcn_s_setprio(0);

        // ---- tree-reduced max (depth 5 + 1 cross-half shuffle)
        float tm[16];
#pragma unroll
        for (int r = 0; r < 16; ++r) tm[r] = fmaxf(sa0[r], sa1[r]);
#pragma unroll
        for (int st = 8; st >= 1; st >>= 1)
#pragma unroll
            for (int r = 0; r < st; ++r) tm[r] = fmaxf(tm[r], tm[r + st]);
        float pmax = tm[0];
        pmax = fmaxf(pmax, __shfl_xor(pmax, 32));

        // ---- defer-max: rescale only when max grew by > 8 (exp2 domain)
        if (__any(pmax > m_i + 8.0f)) {
            float nm = fmaxf(m_i, pmax);
            float f  = exp2a(m_i - nm);
            l_i *= f; m_i = nm;
#pragma unroll
            for (int ct = 0; ct < 4; ++ct)
#pragma unroll
                for (int r = 0; r < 16; ++r) O[ct][r] *= f;
        }

        // ---- P = exp2(s - m), tree-reduced row sum
#pragma unroll
        for (int r = 0; r < 16; ++r) sa0[r] = exp2a(sa0[r] - m_i);
#pragma unroll
        for (int r = 0; r < 16; ++r) sa1[r] = exp2a(sa1[r] - m_i);
        float ts[16];
#pragma unroll
        for (int r = 0; r < 16; ++r) ts[r] = sa0[r] + sa1[r];
#pragma unroll
        for (int st = 8; st >= 1; st >>= 1)
#pragma unroll
            for (int r = 0; r < st; ++r) ts[r] += ts[r + st];
        float rs = ts[0];
        rs += __shfl_xor(rs, 32);
        l_i += rs;

        // ---- pack P (v_cvt_pk_bf16_f32), build PV B-frags via permlane32
        union { unsigned u[4]; bf16x8 v; } pf0, pf1, pf2, pf3;
        {
            unsigned w0 = cvtpk(sa0[0],  sa0[1]),  w1 = cvtpk(sa0[2],  sa0[3]);
            unsigned w2 = cvtpk(sa0[4],  sa0[5]),  w3 = cvtpk(sa0[6],  sa0[7]);
            unsigned w4 = cvtpk(sa0[8],  sa0[9]),  w5 = cvtpk(sa0[10], sa0[11]);
            unsigned w6 = cvtpk(sa0[12], sa0[13]), w7 = cvtpk(sa0[14], sa0[15]);
            asm("v_permlane32_swap_b32 %0, %1" : "+v"(w0), "+v"(w2));
            asm("v_permlane32_swap_b32 %0, %1" : "+v"(w1), "+v"(w3));
            asm("v_permlane32_swap_b32 %0, %1" : "+v"(w4), "+v"(w6));
            asm("v_permlane32_swap_b32 %0, %1" : "+v"(w5), "+v"(w7));
            pf0.u[0] = w0; pf0.u[1] = w1; pf0.u[2] = w2; pf0.u[3] = w3;
            pf1.u[0] = w4; pf1.u[1] = w5; pf1.u[2] = w6; pf1.u[3] = w7;
        }
        {
            unsigned w0 = cvtpk(sa1[0],  sa1[1]),  w1 = cvtpk(sa1[2],  sa1[3]);
            unsigned w2 = cvtpk(sa1[4],  sa1[5]),  w3 = cvtpk(sa1[6],  sa1[7]);
            unsigned w4 = cvtpk(sa1[8],  sa1[9]),  w5 = cvtpk(sa1[10], sa1[11]);
            unsigned w6 = cvtpk(sa1[12], sa1[13]), w7 = cvtpk(sa1[14], sa1[15]);
            asm("v_permlane32_swap_b32 %0, %1" : "+v"(w0), "+v"(w2));
            asm("v_permlane32_swap_b32 %0, %1" : "+v"(w1), "+v"(w3));
            asm("v_permlane32_swap_b32 %0, %1" : "+v"(w4), "+v"(w6));
            asm("v_permlane32_swap_b32 %0, %1" : "+v"(w5), "+v"(w7));
            pf2.u[0] = w0; pf2.u[1] = w1; pf2.u[2] = w2; pf2.u[3] = w3;
            pf3.u[0] = w4; pf3.u[1] = w5; pf3.u[2] = w6; pf3.u[3] = w7;
        }

        // ---- O^T += V P^T ; V A-frags from LDS
        __builtin_amdgcn_s_setprio(1);
#pragma unroll
        for (int ct = 0; ct < 4; ++ct) {
            const char* vrow = Vt + (ct * 32 + l31) * 128;
            bf16x8 v0 = *(const bf16x8*)(vrow + ((0 + h) ^ vrsw) * 16);
            bf16x8 v1 = *(const bf16x8*)(vrow + ((2 + h) ^ vrsw) * 16);
            bf16x8 v2 = *(const bf16x8*)(vrow + ((4 + h) ^ vrsw) * 16);
            bf16x8 v3 = *(const bf16x8*)(vrow + ((6 + h) ^ vrsw) * 16);
            O[ct] = MFMA32(v0, pf0.v, O[ct]);
            O[ct] = MFMA32(v1, pf1.v, O[ct]);
            O[ct] = MFMA32(v2, pf2.v, O[ct]);
            O[ct] = MFMA32(v3, pf3.v, O[ct]);
        }
        __builtin_amdgcn_s_setprio(0);

        __syncthreads();              // all waves done reading Ks/Vt
        if (t + 1 < t1) {
#pragma unroll
            for (int i = 0; i < 4; ++i) *(bf16x8*)(Kd + ((kgb + i) ^ ksz) * 16) = kreg[i];
#pragma unroll
            for (int i = 0; i < 4; ++i) *(bf16x8*)(Vd + ((vgb + i) ^ vsz) * 16) = vreg[i];
        }
        __syncthreads();
    }

    // ---- epilogue: unnormalized O~ -> smem [128 q][256B] bf16, coalesced out
    const int qrow = wv * 32 + l31;
    const int esw  = (qrow & 7) << 4;
#pragma unroll
    for (int ct = 0; ct < 4; ++ct)
#pragma unroll
        for (int i = 0; i < 8; ++i) {
            int c = ct * 32 + 2 * (i & 1) + 8 * (i >> 1) + 4 * h;
            unsigned u = pack2bf(O[ct][2 * i], O[ct][2 * i + 1]);
            *(unsigned*)(smem + qrow * 256 + ((c * 2) ^ esw)) = u;
        }
    __syncthreads();
    __hip_bfloat16* pbase = (s < 4) ? (PO0 + (size_t)s * NB * HW * CH) : PO4;
    __hip_bfloat16* pg = pbase + ((size_t)n * HW + q0) * CH;
#pragma unroll
    for (int it = 0; it < 8; ++it) {
        int ch = it * 256 + tid, r = ch >> 4, g = ch & 15;
        if (q0 + r < HW) {
            bf16x8 v = *(const bf16x8*)(smem + r * 256 + ((g * 16) ^ ((r & 7) << 4)));
            *(bf16x8*)(pg + (size_t)r * CH + g * 8) = v;
        }
    }
    if (h == 0 && qg < HW) {
        size_t base = (size_t)(s * NB + n) * HW + qg;
        Mbuf[base] = m_i; Lbuf[base] = l_i;
    }
}

// ---------------------------------------------------------------------------
// Kernel 2b: merge KV-split partials -> att bf16 in WORKSPACE (restored as a
// separate kernel: PO regions alias `out`, so the merge must fully drain
// before zbn writes out — fusing it into zbn raced (R17 NaN)).
// ---------------------------------------------------------------------------
__global__ __launch_bounds__(256) void merge_kernel(
        const __hip_bfloat16* __restrict__ PO0,
        const __hip_bfloat16* __restrict__ PO4,
        const float* __restrict__ Mbuf,
        const float* __restrict__ Lbuf,
        __hip_bfloat16* __restrict__ att) {
    const int idx = blockIdx.x * 256 + threadIdx.x;
    const int nq = idx >> 4;
    const int c0 = (idx & 15) * 8;
    const size_t NHW = (size_t)NB * HW;

    float m[NSPLIT], l[NSPLIT];
#pragma unroll
    for (int s = 0; s < NSPLIT; ++s) { m[s] = Mbuf[s * NHW + nq]; l[s] = Lbuf[s * NHW + nq]; }
    float M = m[0];
#pragma unroll
    for (int s = 1; s < NSPLIT; ++s) M = fmaxf(M, m[s]);
    float w[NSPLIT], denom = 0.f;
#pragma unroll
    for (int s = 0; s < NSPLIT; ++s) { w[s] = exp2f(m[s] - M); denom += w[s] * l[s]; }
    float rinv = 1.f / denom;

    float acc[8] = {};
#pragma unroll
    for (int s = 0; s < NSPLIT; ++s) {
        const __hip_bfloat16* pbase = (s < 4) ? (PO0 + (size_t)s * NHW * CH) : PO4;
        union { bf16x8 v; unsigned short u[8]; } p;
        p.v = *(const bf16x8*)(pbase + (size_t)nq * CH + c0);
#pragma unroll
        for (int j = 0; j < 8; ++j) acc[j] += w[s] * bfraw2f(p.u[j]);
    }
    union { bf16x8 v; unsigned short u[8]; } ov;
#pragma unroll
    for (int j = 0; j < 8; ++j) ov.u[j] = (unsigned short)f2bf(acc[j] * rinv);
    *(bf16x8*)(att + (size_t)nq * CH + c0) = ov.v;
}

// ---------------------------------------------------------------------------
// Kernel 3: z = ZwB @ att[n] via MFMA (K=128), BN + residual, grid.x = 56.
// (R15 version: reads merged att from workspace.)
// ---------------------------------------------------------------------------
__global__ __launch_bounds__(256) void zbn_kernel(const __hip_bfloat16* __restrict__ att,
                                                  const __hip_bfloat16* __restrict__ ZwB,
                                                  const float* __restrict__ gamma,
                                                  const float* __restrict__ beta,
                                                  const float* __restrict__ mean,
                                                  const float* __restrict__ var,
                                                  const float* __restrict__ x,
                                                  float* __restrict__ out) {
    const int q0 = blockIdx.x * 64;
    if (q0 >= HW) return;             // grid.x padded to 56 for XCD alignment
    const int n  = blockIdx.z;
    const int m0 = blockIdx.y * 64;
    const int tid = threadIdx.x;
    const int lane = tid & 63, wv = tid >> 6;
    const int lr = lane & 15, hi = lane >> 4;

    __shared__ char smem[32768];
    char* Az = smem;
    char* Ba = smem + 16384;

#pragma unroll
    for (int it = 0; it < 4; ++it) {
        int ch = it * 256 + tid, r = ch >> 4, o = ch & 15;
        int sw = (o * 16) ^ ((r & 7) << 4);
        bf16x8 a = *(const bf16x8*)(ZwB + (size_t)(m0 + r) * CH + o * 8);
        *(bf16x8*)(Az + r * 256 + sw) = a;
        bf16x8 b = *(const bf16x8*)(att + ((size_t)n * HW + q0 + r) * CH + o * 8);
        *(bf16x8*)(Ba + r * 256 + sw) = b;
    }
    __syncthreads();

    f32x4 acc[4] = {};
    const int mrow = wv * 16 + lr;
#pragma unroll
    for (int ks = 0; ks < 4; ++ks) {
        bf16x8 af = *(const bf16x8*)(Az + mrow * 256 +
                                     ((ks * 64 + hi * 16) ^ ((mrow & 7) << 4)));
#pragma unroll
        for (int kn = 0; kn < 4; ++kn) {
            int qrow = kn * 16 + lr;
            bf16x8 bfr = *(const bf16x8*)(Ba + qrow * 256 +
                                          ((ks * 64 + hi * 16) ^ ((qrow & 7) << 4)));
            acc[kn] = MFMA16(af, bfr, acc[kn]);
        }
    }
    __syncthreads();

    float inv[4], add[4];
#pragma unroll
    for (int reg = 0; reg < 4; ++reg) {
        int m = m0 + wv * 16 + hi * 4 + reg;
        inv[reg] = gamma[m] * rsqrtf(var[m] + BNEPS);
        add[reg] = beta[m] - mean[m] * inv[reg];
    }

#pragma unroll
    for (int kn = 0; kn < 4; ++kn)
#pragma unroll
        for (int reg = 0; reg < 4; ++reg) {
            int row = wv * 16 + hi * 4 + reg;
            int colb = (kn * 16 + lr) * 4;
            *(float*)(smem + row * 256 + (colb ^ ((row & 7) << 4))) =
                acc[kn][reg] * inv[reg] + add[reg];
        }
    __syncthreads();

#pragma unroll
    for (int it = 0; it < 4; ++it) {
        int ch = it * 256 + tid, rr = ch >> 4, o = ch & 15;
        f32x4 v = *(const f32x4*)(smem + rr * 256 + ((o * 16) ^ ((rr & 7) << 4)));
        size_t idx = (size_t)n * CIN * HW + (size_t)(m0 + rr) * HW + q0 + o * 4;
        float4 xv = *(const float4*)(x + idx);
        float4 ov; ov.x = v[0] + xv.x; ov.y = v[1] + xv.y;
                   ov.z = v[2] + xv.z; ov.w = v[3] + xv.w;
        *(float4*)(out + idx) = ov;
    }
}

// ---------------------------------------------------------------------------
extern "C" void kernel_launch(void* const* d_in, const int* in_sizes, int n_in,
                              void* d_out, int out_size, void* d_ws, size_t ws_size,
                              hipStream_t stream) {
    const float* x     = (const float*)d_in[0];
    const float* Ww    = (const float*)d_in[1];
    const float* Wb    = (const float*)d_in[2];
    const float* Zw    = (const float*)d_in[3];
    const float* gamma = (const float*)d_in[4];
    const float* beta  = (const float*)d_in[5];
    const float* mean  = (const float*)d_in[6];
    const float* var   = (const float*)d_in[7];
    float* out = (float*)d_out;

    // d_out scratch chain (51.38 MB), all dead before zbn writes out:
    //   [25.69, 44.96M)  Qt/Kt/Vg      (proj -> attn)
    //   [0, 25.69M)      PO splits 0-3 (attn -> merge)
    //   [44.96, 51.38M)  PO split 4    (tail, exactly 6.42MB)
    const size_t xT_bytes  = (size_t)NB * HW * CIN * 2;   // region size kept for layout
    const size_t qkv_bytes = (size_t)NB * HW * CH * 2;
    char* ob = (char*)d_out;
    __hip_bfloat16* Qt  = (__hip_bfloat16*)(ob + xT_bytes);
    __hip_bfloat16* Kt  = (__hip_bfloat16*)(ob + xT_bytes + qkv_bytes);
    __hip_bfloat16* Vgb = (__hip_bfloat16*)(ob + xT_bytes + 2 * qkv_bytes);
    __hip_bfloat16* PO0 = (__hip_bfloat16*)ob;
    __hip_bfloat16* PO4 = (__hip_bfloat16*)(ob + xT_bytes + 3 * qkv_bytes);

    // workspace: attb + weights + m/l (~8 MB, proven available)
    char* w = (char*)d_ws;
    __hip_bfloat16* attb = (__hip_bfloat16*)w;                       w += qkv_bytes;
    __hip_bfloat16* WwB  = (__hip_bfloat16*)w;                       w += (size_t)TCH * CIN * 2;
    __hip_bfloat16* ZwB  = (__hip_bfloat16*)w;                       w += (size_t)CIN * CH * 2;
    float* Mbuf = (float*)w;                                         w += (size_t)NSPLIT * NB * HW * 4;
    float* Lbuf = (float*)w;

    cvt_wts<<<dim3(256), 256, 0, stream>>>(Ww, Zw, WwB, ZwB);
    proj_kernel<<<dim3(56, TCH / 64, NB), 256, 0, stream>>>(x, WwB, Wb, Qt, Kt, Vgb);
    attn_kernel<<<dim3(NB * NSPLIT, (HW + QB - 1) / QB), 256, 0, stream>>>(
        Qt, Kt, Vgb, PO0, PO4, Mbuf, Lbuf);
    merge_kernel<<<dim3(NB * HW * 16 / 256), 256, 0, stream>>>(PO0, PO4, Mbuf, Lbuf, attb);
    zbn_kernel<<<dim3(56, CIN / 64, NB), 256, 0, stream>>>(attb, ZwB, gamma, beta,
                                                           mean, var, x, out);
}